// Round 3
// baseline (884.828 us; speedup 1.0000x reference)
//
#include <hip/hip_runtime.h>

#define HID 50
#define FOURH 200
#define TSTEPS 2048
#define NBATCH 1024

#define LOG2E 1.44269504f

typedef _Float16 half8 __attribute__((ext_vector_type(8)));
typedef float    f32x4 __attribute__((ext_vector_type(4)));

__device__ __forceinline__ float frcp(float x)  { return __builtin_amdgcn_rcpf(x); }
__device__ __forceinline__ float fexp2(float x) { return __builtin_amdgcn_exp2f(x); }

// Issue-bound regime (r0->r2 probe: dur tracks VALU inst count). Replace the
// 101 fdot2/step with 32 MFMA on the matrix pipe.
//
// Layout: Wh columns re-packed with each gate padded to 64 cols (256 total,
// 16 tiles of 16). Column 64w+u = u (mod 16), so lane u's own-unit z for gate
// w sits in acc[4w + (u>>4)] on lane u itself -> gate extraction is 12
// v_cndmask, zero cross-lane traffic. A-operand: h broadcast into all 16 rows
// (row-layout-immune) via 2 ds_read_b128 of hbuf at 4 uniform addresses per
// 16-lane group. Scales: i/f/o weight cols pre-scaled by log2e, g cols by
// 2*log2e (folds tanh's 2x into the weights).
__global__ __launch_bounds__(64, 1)
void lstm_mfma_kernel(const float* __restrict__ x,
                      const float* __restrict__ Wx,
                      const float* __restrict__ Wh,
                      const float* __restrict__ bias,
                      const float* __restrict__ Wd,
                      const float* __restrict__ bd,
                      float* __restrict__ out) {
    const int b    = blockIdx.x;
    const int lane = threadIdx.x;
    const int g    = lane >> 4;          // 16-lane group 0..3
    const int cl   = lane & 15;          // col-within-tile
    const int lc   = (lane < HID) ? lane : (HID - 1);

    __shared__ __align__(16) float    xs[TSTEPS + 4];
    __shared__ __align__(16) _Float16 hbuf[80];  // [0..63] h padded ([50..63]==0), [64..77] scratch

    // Stage x (coalesced float4 loads).
    const float4* xb4 = (const float4*)(x + (size_t)b * TSTEPS);
    float4* xs4 = (float4*)xs;
    #pragma unroll
    for (int i = lane; i < TSTEPS / 4; i += 64) xs4[i] = xb4[i];
    if (lane == 0) xs[TSTEPS] = 0.0f;
    for (int i = lane; i < 80; i += 64) hbuf[i] = (_Float16)0.0f;

    // B fragments: 16 N-tiles x 2 K-slices, 8 halves per lane each.
    // B[k][cp]: cp = 16n + cl (padded col), k = s*32 + g*8 + j.
    half8 bf[32];
    #pragma unroll
    for (int n = 0; n < 16; ++n) {
        const int cp = 16 * n + cl;
        const int w  = cp >> 6;      // gate 0..3
        const int u  = cp & 63;      // unit within gate (pad if >=50)
        const float sc = (w == 2) ? (2.0f * LOG2E) : LOG2E;
        #pragma unroll
        for (int s = 0; s < 2; ++s) {
            half8 hb;
            #pragma unroll
            for (int j = 0; j < 8; ++j) {
                const int k = s * 32 + g * 8 + j;
                float v = 0.0f;
                if (k < HID && u < HID) v = sc * Wh[k * FOURH + w * HID + u];
                hb[j] = (_Float16)v;
            }
            bf[2 * n + s] = hb;
        }
    }

    const float wx_i = LOG2E * Wx[lc],                  b_i = LOG2E * bias[lc];
    const float wx_f = LOG2E * Wx[HID + lc],            b_f = LOG2E * bias[HID + lc];
    const float wx_g = 2.0f * LOG2E * Wx[2 * HID + lc], b_g = 2.0f * LOG2E * bias[2 * HID + lc];
    const float wx_o = LOG2E * Wx[3 * HID + lc],        b_o = LOG2E * bias[3 * HID + lc];

    // Branchless h-write slot: real units -> [0..49], dup lanes -> [64..77].
    const int widx = (lane < HID) ? lane : (lane + 14);

    float c = 0.0f;
    float h = 0.0f;
    __syncthreads();   // one-time: staging visible

    float xt = xs[0];
    const f32x4 zero4 = {0.0f, 0.0f, 0.0f, 0.0f};

    for (int t = 0; t < TSTEPS; ++t) {
        const float xt_next = xs[t + 1];

        // A operand: h[8g..8g+7] (slice0) and h[32+8g..39+8g] (slice1, zero-padded).
        const half8 a0 = *(const half8*)(hbuf + g * 8);
        const half8 a1 = *(const half8*)(hbuf + 32 + g * 8);

        f32x4 acc[16];
        #pragma unroll
        for (int n = 0; n < 16; ++n)
            acc[n] = __builtin_amdgcn_mfma_f32_16x16x32_f16(a0, bf[2 * n], zero4, 0, 0, 0);
        #pragma unroll
        for (int n = 0; n < 16; ++n)
            acc[n] = __builtin_amdgcn_mfma_f32_16x16x32_f16(a1, bf[2 * n + 1], acc[n], 0, 0, 0);

        // Gate w's z for unit u=lane lives in acc[4w + g] (any reg; rows identical).
        const bool g1 = (g & 1) != 0;
        const bool g2 = (g & 2) != 0;
        float zd0, zd1, zd2, zd3;
        {
            const float v01 = g1 ? acc[1][0]  : acc[0][0];
            const float v23 = g1 ? acc[3][0]  : acc[2][0];
            zd0 = g2 ? v23 : v01;
        }
        {
            const float v01 = g1 ? acc[5][0]  : acc[4][0];
            const float v23 = g1 ? acc[7][0]  : acc[6][0];
            zd1 = g2 ? v23 : v01;
        }
        {
            const float v01 = g1 ? acc[9][0]  : acc[8][0];
            const float v23 = g1 ? acc[11][0] : acc[10][0];
            zd2 = g2 ? v23 : v01;
        }
        {
            const float v01 = g1 ? acc[13][0] : acc[12][0];
            const float v23 = g1 ? acc[15][0] : acc[14][0];
            zd3 = g2 ? v23 : v01;
        }

        const float zi = fmaf(xt, wx_i, b_i) + zd0;
        const float zf = fmaf(xt, wx_f, b_f) + zd1;
        const float zg = fmaf(xt, wx_g, b_g) + zd2;   // already 2*log2e scaled
        const float zo = fmaf(xt, wx_o, b_o) + zd3;

        const float ig = frcp(1.0f + fexp2(-zi));
        const float fg = frcp(1.0f + fexp2(-zf));
        const float og = frcp(1.0f + fexp2(-zo));
        const float gg = fmaf(-2.0f, frcp(fexp2(zg) + 1.0f), 1.0f);
        c = fmaf(fg, c, ig * gg);
        const float tc = fmaf(-2.0f, frcp(fexp2((2.0f * LOG2E) * c) + 1.0f), 1.0f);
        h = og * tc;

        hbuf[widx] = (_Float16)h;   // same-wave DS ordering; read next iter
        xt = xt_next;
    }

    // out[b] = h_T . Wd + bd  (fp32 h from registers)
    float v = (lane < HID) ? h * Wd[lane] : 0.0f;
    #pragma unroll
    for (int off = 32; off > 0; off >>= 1) v += __shfl_down(v, off);
    if (lane == 0) out[b] = v + bd[0];
}

extern "C" void kernel_launch(void* const* d_in, const int* in_sizes, int n_in,
                              void* d_out, int out_size, void* d_ws, size_t ws_size,
                              hipStream_t stream) {
    const float* x    = (const float*)d_in[0];  // [1024, 2048, 1]
    const float* Wx   = (const float*)d_in[1];  // [1, 200]
    const float* Wh   = (const float*)d_in[2];  // [50, 200]
    const float* bias = (const float*)d_in[3];  // [200]
    const float* Wd   = (const float*)d_in[4];  // [50, 1]
    const float* bd   = (const float*)d_in[5];  // [1]
    float* out = (float*)d_out;                 // [1024, 1]

    lstm_mfma_kernel<<<dim3(NBATCH), dim3(64), 0, stream>>>(
        x, Wx, Wh, bias, Wd, bd, out);
}